// Round 2
// baseline (190680.457 us; speedup 1.0000x reference)
//
#include <hip/hip_runtime.h>
#include <math.h>

#define Bn 256
#define Sn 1024
#define Ln 32
#define En 128
#define Hn 256
#define Mn 10
#define OUTn 121
#define K1 387
#define K1P 416      // 32*13
#define W1c 13
#define K2 640       // 32*20
#define W2c 20
#define NWG 256
#define NTHR 256

#define BLK1 (Bn * K1P)   // 106496
#define BLK2 (Bn * K2)    // 163840

__device__ __forceinline__ float sigmoidf_(float x) {
    return 1.0f / (1.0f + __expf(-x));
}
__device__ __forceinline__ float tanhf_(float x) {
    return 1.0f - 2.0f / (__expf(2.0f * x) + 1.0f);
}
__device__ __forceinline__ float softplus_(float x) {
    return (x > 20.0f) ? x : log1pf(__expf(x));
}

// ---------------- init / pack ----------------
__global__ __launch_bounds__(256) void init_pack(
    const float* __restrict__ Watt, const float* __restrict__ Wout,
    const float* __restrict__ traj,
    float* __restrict__ WattT, float* __restrict__ WoutT, float* __restrict__ x1a)
{
    int idx = blockIdx.x * 256 + threadIdx.x;
    if (idx < K1P * 32) {                      // WattT[k][m], m-pad 32
        int k = idx >> 5, m = idx & 31;
        WattT[idx] = (m < 30 && k < K1) ? Watt[m * K1 + k] : 0.f;
    }
    if (idx < Hn * En) {                       // WoutT[k][r], r-pad 128
        int k = idx >> 7, r = idx & 127;
        WoutT[idx] = (r < OUTn) ? Wout[r * Hn + k] : 0.f;
    }
    if (idx < Bn * 3) {                        // traj(t=0) into x1buf[0]
        int b = idx / 3, j = idx - b * 3;
        x1a[b * K1P + 128 + j] = traj[(size_t)b * Sn * 3 + j];
    }
}

// ---------------- grid barrier ----------------
__device__ __forceinline__ void gsync(unsigned* cnt, unsigned* gen)
{
    __threadfence();          // release all prior global writes (drains + inv)
    __syncthreads();
    if (threadIdx.x == 0) {
        unsigned g = __hip_atomic_load(gen, __ATOMIC_RELAXED, __HIP_MEMORY_SCOPE_AGENT);
        unsigned arrived = __hip_atomic_fetch_add(cnt, 1u, __ATOMIC_ACQ_REL,
                                                  __HIP_MEMORY_SCOPE_AGENT) + 1u;
        if (arrived == NWG) {
            __hip_atomic_store(cnt, 0u, __ATOMIC_RELAXED, __HIP_MEMORY_SCOPE_AGENT);
            __hip_atomic_store(gen, g + 1u, __ATOMIC_RELEASE, __HIP_MEMORY_SCOPE_AGENT);
        } else {
            while (__hip_atomic_load(gen, __ATOMIC_ACQUIRE, __HIP_MEMORY_SCOPE_AGENT) == g)
                __builtin_amdgcn_s_sleep(1);
        }
    }
    __syncthreads();
    __threadfence();          // acquire: invalidate L1 before reading peers' data
}

// ---------------- one LSTM layer (gates GEMM + cell), weights in regs ----------------
template <int WW, int KP>
__device__ __forceinline__ void gates_layer(
    const float (&wreg)[4][WW], const float bv[4], float& c,
    const float* __restrict__ xsrc,      // [Bn][KP]
    float* __restrict__ dst1, int st1,   // hnext -> dst1[b*st1 + h]
    float* __restrict__ dst2, int st2,   // optional second copy (may be null)
    float* __restrict__ red, float* __restrict__ gatebuf,
    int tid, int hu, int sl, int b0, int h, int bcell)
{
    for (int bc = 0; bc < 4; ++bc) {
        float acc[4][8];
#pragma unroll
        for (int g = 0; g < 4; ++g)
#pragma unroll
            for (int b8 = 0; b8 < 8; ++b8) acc[g][b8] = 0.f;

#pragma unroll
        for (int b8 = 0; b8 < 8; ++b8) {
            const float* xp = xsrc + (size_t)(b0 + bc * 8 + b8) * KP + sl * WW;
            if (WW == W2c) {
                const float4* xp4 = (const float4*)xp;
#pragma unroll
                for (int q = 0; q < 5; ++q) {
                    float4 xq = xp4[q];
#pragma unroll
                    for (int g = 0; g < 4; ++g) {
                        acc[g][b8] = fmaf(wreg[g][q * 4 + 0], xq.x, acc[g][b8]);
                        acc[g][b8] = fmaf(wreg[g][q * 4 + 1], xq.y, acc[g][b8]);
                        acc[g][b8] = fmaf(wreg[g][q * 4 + 2], xq.z, acc[g][b8]);
                        acc[g][b8] = fmaf(wreg[g][q * 4 + 3], xq.w, acc[g][b8]);
                    }
                }
            } else {
#pragma unroll
                for (int j = 0; j < WW; ++j) {
                    float xj = xp[j];
#pragma unroll
                    for (int g = 0; g < 4; ++g)
                        acc[g][b8] = fmaf(wreg[g][j], xj, acc[g][b8]);
                }
            }
        }
        // partials -> LDS  (row = hu*4+g local in [0,32), stride 33: conflict-free)
#pragma unroll
        for (int g = 0; g < 4; ++g)
#pragma unroll
            for (int b8 = 0; b8 < 8; ++b8)
                red[((hu * 4 + g) * 8 + b8) * 33 + sl] = acc[g][b8];
        __syncthreads();
        // reduce 32 slices: thread t handles (row=t>>3, b8=t&7) == linear t
        {
            const float* rp = red + tid * 33;
            float s = 0.f;
#pragma unroll 8
            for (int j = 0; j < 32; ++j) s += rp[j];
            gatebuf[tid] = s;
        }
        __syncthreads();
        // cell update: threads whose bcell is in this chunk
        if ((sl >> 3) == bc) {
            int bloc = sl & 7;
            float I = sigmoidf_(gatebuf[(hu * 4 + 0) * 8 + bloc] + bv[0]);
            float F = sigmoidf_(gatebuf[(hu * 4 + 1) * 8 + bloc] + bv[1]);
            float G = tanhf_   (gatebuf[(hu * 4 + 2) * 8 + bloc] + bv[2]);
            float O = sigmoidf_(gatebuf[(hu * 4 + 3) * 8 + bloc] + bv[3]);
            c = fmaf(F, c, I * G);
            float hn = O * tanhf_(c);
            dst1[(size_t)bcell * st1 + h] = hn;
            if (dst2) dst2[(size_t)bcell * st2 + h] = hn;
        }
    }
}

// ---------------- persistent main kernel ----------------
__global__ __launch_bounds__(256, 1) void rnn_main(
    const float* __restrict__ traj, const int* __restrict__ words,
    const int* __restrict__ wlen, const float* __restrict__ emb,
    const float* __restrict__ Wih1, const float* __restrict__ Whh1, const float* __restrict__ b1,
    const float* __restrict__ Wih2, const float* __restrict__ Whh2, const float* __restrict__ b2,
    const float* __restrict__ Wih3, const float* __restrict__ Whh3, const float* __restrict__ b3,
    const float* __restrict__ batt, const float* __restrict__ bout,
    float* __restrict__ x1buf, float* __restrict__ x2buf, float* __restrict__ x3buf,
    const float* __restrict__ WattT, const float* __restrict__ WoutT,
    float* __restrict__ out, unsigned* __restrict__ bar)
{
    const int w = blockIdx.x;
    const int hg = w >> 3, bg = w & 7;
    const int tid = threadIdx.x;
    const int hu = tid >> 5, sl = tid & 31;
    const int b0 = bg * 32;
    const int h = hg * 8 + hu;
    const int bcell = b0 + sl;

    // ---- register-stationary weights ----
    float w1[4][W1c], w2r[4][W2c], w3r[4][W2c];
    float bv1[4], bv2[4], bv3[4];
#pragma unroll
    for (int g = 0; g < 4; ++g) {
        int row = g * 256 + h;
#pragma unroll
        for (int j = 0; j < W1c; ++j) {
            int k = sl * W1c + j;
            w1[g][j] = (k < 131) ? Wih1[row * 131 + k]
                     : (k < K1 ? Whh1[row * 256 + (k - 131)] : 0.f);
        }
#pragma unroll
        for (int j = 0; j < W2c; ++j) {
            int k = sl * W2c + j;
            w2r[g][j] = (k < 384) ? Wih2[row * 384 + k] : Whh2[row * 256 + (k - 384)];
            w3r[g][j] = (k < 384) ? Wih3[row * 384 + k] : Whh3[row * 256 + (k - 384)];
        }
        bv1[g] = b1[g * 256 + h];
        bv2[g] = b2[g * 256 + h];
        bv3[g] = b3[g * 256 + h];
    }
    float c1 = 0.f, c2 = 0.f, c3 = 0.f;
    float kapreg = 0.f;
    float battreg = (tid < 30) ? batt[tid] : 0.f;
    float boutreg = (tid < OUTn) ? bout[tid] : 0.f;

    __shared__ float red[32 * 8 * 33];   // 8448
    __shared__ float gatebuf[256];
    __shared__ float attL[K1];
    __shared__ float pv[32];
    __shared__ float sal[Mn], srb[Mn], skp[Mn];
    __shared__ float phi[Ln + 1];
    __shared__ int   wintL[Ln];
    __shared__ int   lenL;
    __shared__ float h3L[Hn];
    __shared__ float ored[256];

    if (tid < Ln) wintL[tid] = words[w * Ln + tid];
    if (tid == 0) lenL = wlen[w];
    __syncthreads();

    unsigned* cnt = bar;
    unsigned* gen = bar + 1;

    for (int i = 0; i < Sn + 2; ++i) {
        float* x1c = x1buf + (size_t)(i & 1) * BLK1;
        float* x1n = x1buf + (size_t)((i + 1) & 1) * BLK1;
        float* x2c = x2buf + (size_t)(i & 1) * BLK2;
        float* x2p = x2buf + (size_t)((i + 1) & 1) * BLK2;   // (i-1)&1
        float* x3c = x3buf + (size_t)(i & 1) * BLK2;
        float* x3p = x3buf + (size_t)((i + 1) & 1) * BLK2;   // (i-1)&1

        // ================= Phase 1 =================
        if (i < Sn) {
            // gates1(i): x = x1(i); h1(i) -> x1(i+1)[131..387) and x2(i)[0..256)
            gates_layer<W1c, K1P>(w1, bv1, c1, x1c,
                                  x1n + 131, K1P, x2c, K2,
                                  red, gatebuf, tid, hu, sl, b0, h, bcell);
        }
        if (i >= 1 && i <= Sn) {
            // gates2(i-1): x = x2(i-1); h2(i-1) -> x2(i)[384..) and x3(i-1)[0..256)
            gates_layer<W2c, K2>(w2r, bv2, c2, x2p,
                                 x2c + 384, K2, x3p, K2,
                                 red, gatebuf, tid, hu, sl, b0, h, bcell);
        }
        if (i >= 2) {
            // out(i-2): h3(i-2) lives in x3((i-2)+1)[384..) = x3buf[(i-1)&1]
            const float* h3src = x3p + (size_t)w * K2 + 384;
            for (int k = tid; k < Hn; k += 256) h3L[k] = h3src[k];
            __syncthreads();
            {
                int r = tid & 127, half = tid >> 7;
                float s = 0.f;
                int kb = half * 128;
#pragma unroll 8
                for (int k = 0; k < 128; ++k)
                    s = fmaf(WoutT[(kb + k) * 128 + r], h3L[kb + k], s);
                ored[tid] = s;
            }
            __syncthreads();
            if (tid < OUTn) {
                float v = ored[tid] + ored[128 + tid] + boutreg;
                out[((size_t)w * Sn + (i - 2)) * OUTn + tid] = v;
            }
            __syncthreads();
        }
        gsync(cnt, gen);

        // ================= Phase 2 =================
        if (i < Sn) {
            // ---- attention for batch w at step i ----
            const float* x1row = x1c + (size_t)w * K1P;
            const float* x2row = x2c + (size_t)w * K2;
            for (int k = tid; k < K1; k += 256)
                attL[k] = (k < 131) ? x1row[k] : x2row[k - 131];
            __syncthreads();
            {   // p = attin @ Watt^T : thread = (ks = tid>>5, m = tid&31)
                int m = tid & 31, ks = tid >> 5;
                int kb = ks * 49;
                int ke = (kb + 49 < K1) ? kb + 49 : K1;
                float s = 0.f;
                for (int k = kb; k < ke; ++k)
                    s = fmaf(WattT[k * 32 + m], attL[k], s);
                gatebuf[tid] = s;
            }
            __syncthreads();
            if (tid < 32) {
                float s = 0.f;
#pragma unroll
                for (int ks = 0; ks < 8; ++ks) s += gatebuf[ks * 32 + tid];
                pv[tid] = s + battreg;
            }
            __syncthreads();
            if (tid < Mn) {
                float a   = softplus_(pv[tid]);
                float bb_ = fmaxf(softplus_(pv[10 + tid]), 0.01f);
                kapreg    = kapreg + softplus_(pv[20 + tid]) * 0.04f;
                sal[tid] = a;
                srb[tid] = 1.0f / bb_;
                skp[tid] = kapreg;
            }
            __syncthreads();
            if (tid < Ln) {
                float ph = 0.f;
                if (tid < lenL) {
#pragma unroll
                    for (int m = 0; m < Mn; ++m) {
                        float d = skp[m] - (float)tid;
                        ph = fmaf(sal[m], __expf(-d * d * srb[m]), ph);
                    }
                }
                phi[tid] = ph;
            }
            __syncthreads();
            if (tid == 0) {
                float s = 0.f;
                for (int l = 0; l < Ln; ++l) s += phi[l];
                phi[Ln] = 1.0f / (s + 1e-8f);
            }
            __syncthreads();
            if (tid < En) {
                float inv = phi[Ln];
                float a = 0.f;
                for (int l = 0; l < Ln; ++l)
                    a = fmaf(phi[l], emb[wintL[l] * En + tid], a);
                a *= inv;
                x1n[(size_t)w * K1P + tid] = a;          // wv(i) -> x1(i+1)
                x2c[(size_t)w * K2 + 256 + tid] = a;     // -> x2(i)
                x3c[(size_t)w * K2 + 256 + tid] = a;     // -> x3(i)
            }
            if (tid < 3 && (i + 1) < Sn)                 // traj(i+1) -> x1(i+1)
                x1n[(size_t)w * K1P + 128 + tid] =
                    traj[((size_t)w * Sn + (i + 1)) * 3 + tid];
            __syncthreads();
        }
        if (i >= 1 && i <= Sn) {
            // gates3(i-1): x = x3(i-1); h3(i-1) -> x3(i)[384..)
            gates_layer<W2c, K2>(w3r, bv3, c3, x3p,
                                 x3c + 384, K2, (float*)nullptr, 0,
                                 red, gatebuf, tid, hu, sl, b0, h, bcell);
        }
        gsync(cnt, gen);
    }
}

extern "C" void kernel_launch(void* const* d_in, const int* in_sizes, int n_in,
                              void* d_out, int out_size, void* d_ws, size_t ws_size,
                              hipStream_t stream)
{
    const float* traj = (const float*)d_in[0];
    const int*   words = (const int*)d_in[1];
    const int*   wlen  = (const int*)d_in[2];
    const float* emb   = (const float*)d_in[3];
    const float* Wih1  = (const float*)d_in[4];
    const float* Whh1  = (const float*)d_in[5];
    const float* b1    = (const float*)d_in[6];
    const float* Wih2  = (const float*)d_in[7];
    const float* Whh2  = (const float*)d_in[8];
    const float* b2    = (const float*)d_in[9];
    const float* Wih3  = (const float*)d_in[10];
    const float* Whh3  = (const float*)d_in[11];
    const float* b3    = (const float*)d_in[12];
    const float* Watt  = (const float*)d_in[13];
    const float* batt  = (const float*)d_in[14];
    const float* Wout  = (const float*)d_in[15];
    const float* bout  = (const float*)d_in[16];
    float* out = (float*)d_out;

    float* ws = (float*)d_ws;
    float* x1buf = ws;                               // 2*256*416
    float* x2buf = x1buf + 2 * BLK1;                 // 2*256*640
    float* x3buf = x2buf + 2 * BLK2;
    float* WattT = x3buf + 2 * BLK2;                 // 416*32
    float* WoutT = WattT + K1P * 32;                 // 256*128
    unsigned* bar = (unsigned*)(WoutT + Hn * En);    // 2 uints

    size_t total_bytes = (size_t)((2 * BLK1 + 4 * BLK2 + K1P * 32 + Hn * En) * 4 + 8);
    hipMemsetAsync(ws, 0, total_bytes, stream);

    init_pack<<<128, 256, 0, stream>>>(Watt, Wout, traj, WattT, WoutT, x1buf);

    void* args[] = {
        (void*)&traj, (void*)&words, (void*)&wlen, (void*)&emb,
        (void*)&Wih1, (void*)&Whh1, (void*)&b1,
        (void*)&Wih2, (void*)&Whh2, (void*)&b2,
        (void*)&Wih3, (void*)&Whh3, (void*)&b3,
        (void*)&batt, (void*)&bout,
        (void*)&x1buf, (void*)&x2buf, (void*)&x3buf,
        (void*)&WattT, (void*)&WoutT,
        (void*)&out, (void*)&bar
    };
    (void)args;
    rnn_main<<<NWG, NTHR, 0, stream>>>(
        traj, words, wlen, emb,
        Wih1, Whh1, b1, Wih2, Whh2, b2, Wih3, Whh3, b3,
        batt, bout, x1buf, x2buf, x3buf, WattT, WoutT, out, bar);
}

// Round 4
// 97187.189 us; speedup vs baseline: 1.9620x; 1.9620x over previous
//
#include <hip/hip_runtime.h>
#include <math.h>

#define Bn 256
#define Sn 1024
#define Ln 32
#define En 128
#define Hn 256
#define Mn 10
#define OUTn 121
#define K1 387
#define BLK2 (Bn * 640)   // one slot of x2/x3 (rows stride 640)

__device__ __forceinline__ float sigmoidf_(float x) {
    return 1.0f / (1.0f + __expf(-x));
}
__device__ __forceinline__ float tanhf_(float x) {
    return 1.0f - 2.0f / (__expf(2.0f * x) + 1.0f);
}
__device__ __forceinline__ float softplus_(float x) {
    return (x > 20.0f) ? x : log1pf(__expf(x));
}

// ---------------- pack (once per launch) ----------------
// W1p[r=h*4+g][384], k-order [h1(256)|wv(128)]; W1t[r] = {wx0,wx1,wx2,bias}
// WattT[k][32] (30 used); WoutT[k][128] (121 used)
__global__ __launch_bounds__(256) void pack_all(
    const float* __restrict__ Wih1, const float* __restrict__ Whh1,
    const float* __restrict__ b1,
    const float* __restrict__ Watt, const float* __restrict__ Wout,
    float* __restrict__ W1p, float* __restrict__ W1t,
    float* __restrict__ WattT, float* __restrict__ WoutT)
{
    const int bid = blockIdx.x, tid = threadIdx.x;
    if (bid < 1024) {
        int r = bid, h = r >> 2, g = r & 3, row = g * 256 + h;
        for (int k = tid; k < 384; k += 256)
            W1p[(size_t)r * 384 + k] = (k < 256) ? Whh1[row * 256 + k]
                                                 : Wih1[row * 131 + (k - 256)];
        if (tid < 3) W1t[r * 4 + tid] = Wih1[row * 131 + 128 + tid];
        if (tid == 3) W1t[r * 4 + 3] = b1[row];
    } else if (bid < 1152) {
        int idx = (bid - 1024) * 256 + tid;        // 32768 = 256*128
        int k = idx >> 7, rr = idx & 127;
        WoutT[idx] = (rr < OUTn) ? Wout[rr * Hn + k] : 0.f;
    } else {
        int idx = (bid - 1152) * 256 + tid;        // 13312 = 416*32
        if (idx < 13312) {
            int k = idx >> 5, m = idx & 31;
            WattT[idx] = (m < 30 && k < K1) ? Watt[m * K1 + k] : 0.f;
        }
    }
}

// ---------------- dot: 4 gate-rows (g-stride gs) x 4 batches, N4 float4s ----
template <int N4>
__device__ __forceinline__ void dotg(const float* __restrict__ Wb, int gs,
                                     const float* __restrict__ Xb,
                                     float (&acc)[4][4])
{
#pragma unroll 4
    for (int kk = 0; kk < N4; ++kk) {
        float4 wv[4], xv[4];
#pragma unroll
        for (int g = 0; g < 4; ++g)
            wv[g] = *(const float4*)(Wb + (size_t)g * gs + (kk << 2));
#pragma unroll
        for (int bb = 0; bb < 4; ++bb)
            xv[bb] = *(const float4*)(Xb + bb * 640 + (kk << 2));
#pragma unroll
        for (int g = 0; g < 4; ++g)
#pragma unroll
            for (int bb = 0; bb < 4; ++bb) {
                acc[g][bb] = fmaf(wv[g].x, xv[bb].x, acc[g][bb]);
                acc[g][bb] = fmaf(wv[g].y, xv[bb].y, acc[g][bb]);
                acc[g][bb] = fmaf(wv[g].z, xv[bb].z, acc[g][bb]);
                acc[g][bb] = fmaf(wv[g].w, xv[bb].w, acc[g][bb]);
            }
    }
}

// ---------------- A: gates1(i) + gates2(i-1) + gates3(i-2) ----------------
// 768 WGs = 3 layers x (32 h-tiles x 8 b-tiles). Tile [8h x 4g rows, 32 b].
// Thread: dot phase (ks[0,4) x tr[0,8) x tb[0,8)) -> 4 gates x 4 batches;
// cell phase (th[0,8) x tbb[0,32)).
__global__ __launch_bounds__(256, 3) void kernelA(
    const float* __restrict__ W1p, const float* __restrict__ W1t,
    const float* __restrict__ Wih2, const float* __restrict__ Whh2,
    const float* __restrict__ b2,
    const float* __restrict__ Wih3, const float* __restrict__ Whh3,
    const float* __restrict__ b3,
    const float* __restrict__ traj,
    float* __restrict__ x2b, float* __restrict__ x3b,
    float* __restrict__ cbuf, int i)
{
    __shared__ float red[4 * 32 * 33];   // 16.9 KB
    const int wg = blockIdx.x;
    const int l = wg >> 8, sub = wg & 255;
    const int ht = sub >> 3, bt = sub & 7;
    const int tid = threadIdx.x;
    const int ks = tid >> 6, tr = (tid >> 3) & 7, tb = tid & 7;
    const int p = i & 1, q = (i + 1) & 1;   // q == (i-1)&1

    const float* X; float* d1; float* d2;
    if (l == 0) {                 // gates1(i): X = x2(i-1)[0:384) (+traj epilogue)
        if (i >= Sn) return;
        X  = x2b + (size_t)q * BLK2;
        d1 = x2b + (size_t)p * BLK2;              // h1(i) -> x2(i)[0:256)
        d2 = nullptr;
    } else if (l == 1) {          // gates2(i-1): X = x2(i-1)
        if (i < 1 || i > Sn) return;
        X  = x2b + (size_t)q * BLK2;
        d1 = x2b + (size_t)p * BLK2 + 384;        // h2(i-1) -> x2(i)[384:)
        d2 = x3b + (size_t)q * BLK2;              //         -> x3(i-1)[0:256)
    } else {                      // gates3(i-2): X = x3(i-2)
        if (i < 2) return;
        X  = x3b + (size_t)p * BLK2;              // (i-2)&1 == p
        d1 = x3b + (size_t)q * BLK2 + 384;        // h3(i-2) -> x3(i-1)[384:)
        d2 = nullptr;
    }

    float acc[4][4];
#pragma unroll
    for (int g = 0; g < 4; ++g)
#pragma unroll
        for (int bb = 0; bb < 4; ++bb) acc[g][bb] = 0.f;

    const float* Xr = X + (size_t)(bt * 32 + tb * 4) * 640;
    const int hd = ht * 8 + tr;
    if (l == 0) {
        // packed rows r=hd*4+g consecutive, stride 384; K=384 as 4 slices of 96
        dotg<24>(W1p + (size_t)(hd * 4) * 384 + ks * 96, 384, Xr + ks * 96, acc);
    } else {
        const float* Wih = (l == 1) ? Wih2 : Wih3;
        const float* Whh = (l == 1) ? Whh2 : Whh3;
        // K=640 as 4 slices of 160; Wih rows (g*256+hd)*384, Whh rows (g*256+hd)*256
        if (ks < 2)
            dotg<40>(Wih + (size_t)hd * 384 + ks * 160, 256 * 384, Xr + ks * 160, acc);
        else if (ks == 2) {
            dotg<16>(Wih + (size_t)hd * 384 + 320, 256 * 384, Xr + 320, acc);  // [320,384)
            dotg<24>(Whh + (size_t)hd * 256,       256 * 256, Xr + 384, acc);  // [384,480)
        } else
            dotg<40>(Whh + (size_t)hd * 256 + 96,  256 * 256, Xr + 480, acc);  // [480,640)
    }

#pragma unroll
    for (int g = 0; g < 4; ++g)
#pragma unroll
        for (int bb = 0; bb < 4; ++bb)
            red[ks * 1056 + (tr * 4 + g) * 33 + tb * 4 + bb] = acc[g][bb];
    __syncthreads();

    const int th = tid >> 5, tbb = tid & 31;
    const int hg = ht * 8 + th, bg = bt * 32 + tbb;
    float g4[4];
#pragma unroll
    for (int g = 0; g < 4; ++g) {
        int rl = (th * 4 + g) * 33 + tbb;
        g4[g] = red[rl] + red[1056 + rl] + red[2112 + rl] + red[3168 + rl];
    }
    if (l == 0) {
        const float* tp = traj + ((size_t)bg * Sn + i) * 3;
        float t0 = tp[0], t1 = tp[1], t2 = tp[2];
#pragma unroll
        for (int g = 0; g < 4; ++g) {
            float4 wt = *(const float4*)(W1t + (size_t)(hg * 4 + g) * 4);
            g4[g] += wt.x * t0 + wt.y * t1 + wt.z * t2 + wt.w;   // wt.w = bias
        }
    } else {
        const float* bb_ = (l == 1) ? b2 : b3;
#pragma unroll
        for (int g = 0; g < 4; ++g) g4[g] += bb_[(g << 8) + hg];
    }
    float I = sigmoidf_(g4[0]);
    float F = sigmoidf_(g4[1]);
    float G = tanhf_(g4[2]);
    float O = sigmoidf_(g4[3]);
    float* cp = cbuf + ((size_t)l * Bn + bg) * Hn + hg;
    float c = *cp;
    float cn = fmaf(F, c, I * G);
    *cp = cn;
    float hn = O * tanhf_(cn);
    d1[(size_t)bg * 640 + hg] = hn;
    if (d2) d2[(size_t)bg * 640 + hg] = hn;
}

// ---------------- B: attention(i) + out(i-2) ----------------
__global__ __launch_bounds__(256) void kernelB(
    const float* __restrict__ WattT, const float* __restrict__ batt,
    const float* __restrict__ WoutT, const float* __restrict__ bout,
    const float* __restrict__ emb, const int* __restrict__ words,
    const int* __restrict__ wlen, const float* __restrict__ traj,
    float* __restrict__ x2b, float* __restrict__ x3b,
    float* __restrict__ kap, float* __restrict__ out, int i)
{
    const int w = blockIdx.x, tid = threadIdx.x;
    const int p = i & 1, q = (i + 1) & 1;
    __shared__ float attL[K1];
    __shared__ float buf[256];
    __shared__ float pv[32];
    __shared__ float sal[Mn], srb[Mn], skp[Mn];
    __shared__ float phi[Ln + 1];
    __shared__ int   wintL[Ln];
    __shared__ int   lenL;
    __shared__ float h3L[Hn];

    if (i < Sn) {
        const float* x2p_ = x2b + (size_t)q * BLK2 + (size_t)w * 640;  // x2(i-1)
        const float* x2c_ = x2b + (size_t)p * BLK2 + (size_t)w * 640;  // x2(i)
        for (int k = tid; k < K1; k += 256)
            attL[k] = (k < 128) ? x2p_[256 + k]                        // wv(i-1)
                    : (k < 131) ? traj[((size_t)w * Sn + i) * 3 + (k - 128)]
                                : x2c_[k - 131];                       // h1(i)
        if (tid < Ln) wintL[tid] = words[w * Ln + tid];
        if (tid == 0) lenL = wlen[w];
        __syncthreads();
        {
            int m = tid & 31, kss = tid >> 5;
            int kb = kss * 49, ke = (kb + 49 < K1) ? kb + 49 : K1;
            float s = 0.f;
            for (int k = kb; k < ke; ++k)
                s = fmaf(WattT[k * 32 + m], attL[k], s);
            buf[tid] = s;
        }
        __syncthreads();
        if (tid < 30) {
            float s = batt[tid];
#pragma unroll
            for (int kss = 0; kss < 8; ++kss) s += buf[kss * 32 + tid];
            pv[tid] = s;
        }
        __syncthreads();
        if (tid < Mn) {
            float a   = softplus_(pv[tid]);
            float bb_ = fmaxf(softplus_(pv[10 + tid]), 0.01f);
            float kp  = kap[w * Mn + tid] + softplus_(pv[20 + tid]) * 0.04f;
            kap[w * Mn + tid] = kp;
            sal[tid] = a; srb[tid] = 1.0f / bb_; skp[tid] = kp;
        }
        __syncthreads();
        if (tid < Ln) {
            float ph = 0.f;
            if (tid < lenL) {
#pragma unroll
                for (int m = 0; m < Mn; ++m) {
                    float d = skp[m] - (float)tid;
                    ph = fmaf(sal[m], __expf(-d * d * srb[m]), ph);
                }
            }
            phi[tid] = ph;
        }
        __syncthreads();
        if (tid == 0) {
            float s = 0.f;
            for (int l = 0; l < Ln; ++l) s += phi[l];
            phi[Ln] = 1.0f / (s + 1e-8f);
        }
        __syncthreads();
        if (tid < En) {
            float inv = phi[Ln];
            float a = 0.f;
            for (int l = 0; l < Ln; ++l)
                a = fmaf(phi[l], emb[wintL[l] * En + tid], a);
            a *= inv;
            x2b[(size_t)p * BLK2 + (size_t)w * 640 + 256 + tid] = a;  // wv(i) -> x2(i)
            x3b[(size_t)p * BLK2 + (size_t)w * 640 + 256 + tid] = a;  //       -> x3(i)
        }
    }
    if (i >= 2) {
        __syncthreads();
        const float* h3src = x3b + (size_t)q * BLK2 + (size_t)w * 640 + 384; // h3(i-2)
        for (int k = tid; k < Hn; k += 256) h3L[k] = h3src[k];
        __syncthreads();
        {
            int r = tid & 127, half = tid >> 7;
            float s = 0.f;
            int kb = half * 128;
#pragma unroll 8
            for (int k = 0; k < 128; ++k)
                s = fmaf(WoutT[(kb + k) * 128 + r], h3L[kb + k], s);
            buf[tid] = s;
        }
        __syncthreads();
        if (tid < OUTn)
            out[((size_t)w * Sn + (i - 2)) * OUTn + tid] =
                buf[tid] + buf[128 + tid] + bout[tid];
    }
}

extern "C" void kernel_launch(void* const* d_in, const int* in_sizes, int n_in,
                              void* d_out, int out_size, void* d_ws, size_t ws_size,
                              hipStream_t stream)
{
    const float* traj  = (const float*)d_in[0];
    const int*   words = (const int*)d_in[1];
    const int*   wlen  = (const int*)d_in[2];
    const float* emb   = (const float*)d_in[3];
    const float* Wih1  = (const float*)d_in[4];
    const float* Whh1  = (const float*)d_in[5];
    const float* b1    = (const float*)d_in[6];
    const float* Wih2  = (const float*)d_in[7];
    const float* Whh2  = (const float*)d_in[8];
    const float* b2    = (const float*)d_in[9];
    const float* Wih3  = (const float*)d_in[10];
    const float* Whh3  = (const float*)d_in[11];
    const float* b3    = (const float*)d_in[12];
    const float* Watt  = (const float*)d_in[13];
    const float* batt  = (const float*)d_in[14];
    const float* Wout  = (const float*)d_in[15];
    const float* bout  = (const float*)d_in[16];
    float* out = (float*)d_out;

    // ws layout (floats) — total ~1.30 M floats = 5.0 MB (round 1's proven 9.3 MB fit)
    float* ws    = (float*)d_ws;
    float* x2b   = ws;                          // 2*BLK2 = 327,680
    float* x3b   = x2b + 2 * (size_t)BLK2;      // 327,680
    float* cbuf  = x3b + 2 * (size_t)BLK2;      // 3*256*256 = 196,608
    float* kap   = cbuf + 3 * Bn * Hn;          // 2,560
    float* W1p   = kap + Bn * Mn;               // 393,216
    float* W1t   = W1p + (size_t)1024 * 384;    // 4,096
    float* WattT = W1t + 4096;                  // 13,312
    float* WoutT = WattT + 13312;               // 32,768

    size_t zfloats = 4 * (size_t)BLK2 + 3 * Bn * Hn + Bn * Mn;
    hipMemsetAsync(ws, 0, zfloats * sizeof(float), stream);
    pack_all<<<1204, 256, 0, stream>>>(Wih1, Whh1, b1, Watt, Wout,
                                       W1p, W1t, WattT, WoutT);

    for (int i = 0; i <= Sn + 1; ++i) {
        kernelA<<<768, 256, 0, stream>>>(W1p, W1t, Wih2, Whh2, b2,
                                         Wih3, Whh3, b3, traj, x2b, x3b, cbuf, i);
        kernelB<<<256, 256, 0, stream>>>(WattT, batt, WoutT, bout, emb, words,
                                         wlen, traj, x2b, x3b, kap, out, i);
    }
}